// Round 4
// baseline (2010.585 us; speedup 1.0000x reference)
//
#include <hip/hip_runtime.h>

// RGCN 3-layer forward, MI355X — fused aggregate-then-transform.
// Identity used: sum_e x[src_e] @ W_r == (sum_e x[src_e]) @ W_r. Per layer, ONE
// kernel: block owns 128 dst rows; fp32 accumulator lives in MFMA regs across all
// 8 relations + root; per relation, aggregate y_r = A_r x tile into LDS (bf16)
// from cache-resident x, then MFMA with W_r (B-frags from L2-hot wt, no LDS).
// Root (r=8) reads A straight from global x. Epilogue fuses bias+ReLU+bf16 cast.
// Edges counting-sorted by rel*N+dst once per call (atomics in sort are the
// remaining known cost — ~200us).
// NOTE: harness passes integer inputs as int32.

#define DEVI __device__ __forceinline__

typedef __attribute__((ext_vector_type(8))) short bf16x8;
typedef __attribute__((ext_vector_type(4))) float f32x4;

DEVI unsigned short f2b(float f) {
  unsigned int u = __builtin_bit_cast(unsigned int, f);
  unsigned int r = (u + 0x7FFFu + ((u >> 16) & 1u)) >> 16;
  return (unsigned short)r;
}
DEVI float b2f(unsigned short h) {
  unsigned int u = ((unsigned int)h) << 16;
  return __builtin_bit_cast(float, u);
}

// ---------------- counting sort of edges by key = rel*N + dst ----------------

__global__ void k_zero2(int* __restrict__ cnt, int n) {
  int stride = gridDim.x * blockDim.x;
  for (int i = blockIdx.x * blockDim.x + threadIdx.x; i < n; i += stride) cnt[i] = 0;
}

__global__ void k_hist2(const int* __restrict__ et, const int* __restrict__ edst,
                        int* __restrict__ cnt, int N, int E) {
  int stride = gridDim.x * blockDim.x;
  for (int i = blockIdx.x * blockDim.x + threadIdx.x; i < E; i += stride)
    atomicAdd(&cnt[(et[i] & 7) * N + edst[i]], 1);
}

__global__ void k_scan1(const int* __restrict__ cnt, int* __restrict__ offs,
                        int* __restrict__ bsum, int KT) {
  __shared__ int l[256];
  int g = blockIdx.x * 256 + threadIdx.x;
  int v = (g < KT) ? cnt[g] : 0;
  l[threadIdx.x] = v;
  __syncthreads();
  for (int o = 1; o < 256; o <<= 1) {
    int t = (threadIdx.x >= o) ? l[threadIdx.x - o] : 0;
    __syncthreads();
    l[threadIdx.x] += t;
    __syncthreads();
  }
  if (g < KT) offs[g] = l[threadIdx.x] - v;
  if (threadIdx.x == 255) bsum[blockIdx.x] = l[255];
}

__global__ void k_scan2(int* __restrict__ bsum, int nb) {
  __shared__ int l[256];
  __shared__ int carry;
  if (threadIdx.x == 0) carry = 0;
  __syncthreads();
  for (int base = 0; base < nb; base += 256) {
    int g = base + threadIdx.x;
    int v = (g < nb) ? bsum[g] : 0;
    l[threadIdx.x] = v;
    __syncthreads();
    for (int o = 1; o < 256; o <<= 1) {
      int t = (threadIdx.x >= o) ? l[threadIdx.x - o] : 0;
      __syncthreads();
      l[threadIdx.x] += t;
      __syncthreads();
    }
    if (g < nb) bsum[g] = l[threadIdx.x] - v + carry;
    __syncthreads();
    if (threadIdx.x == 0) carry += l[255];
    __syncthreads();
  }
}

__global__ void k_scan3(int* __restrict__ offs, const int* __restrict__ bsum,
                        int* __restrict__ cursor, int KT, int E) {
  int g = blockIdx.x * 256 + threadIdx.x;
  if (g < KT) {
    int v = offs[g] + bsum[blockIdx.x];
    offs[g] = v;
    cursor[g] = v;
  }
  if (g == 0) offs[KT] = E;
}

__global__ void k_fill2(const int* __restrict__ et, const int* __restrict__ esrc,
                        const int* __restrict__ edst, int* __restrict__ cursor,
                        int* __restrict__ src_s, int N, int E) {
  int stride = gridDim.x * blockDim.x;
  for (int i = blockIdx.x * blockDim.x + threadIdx.x; i < E; i += stride) {
    int key = (et[i] & 7) * N + edst[i];
    int pos = atomicAdd(&cursor[key], 1);
    src_s[pos] = esrc[i];
  }
}

// ---------------- weight prep: fp32 [9][128][DOUT] -> bf16 transposed [9][DOUT][128] ----------------

__global__ void wprep_kernel(const float* __restrict__ Wrel, const float* __restrict__ Wroot,
                             unsigned short* __restrict__ wt, int DOUT) {
  int total = 9 * 128 * DOUT;
  int stride = gridDim.x * blockDim.x;
  for (int i = blockIdx.x * blockDim.x + threadIdx.x; i < total; i += stride) {
    int k = i & 127;
    int oo = i >> 7;           // rr*DOUT + o
    int o = oo % DOUT;
    int rr = oo / DOUT;
    float v = (rr < 8) ? Wrel[((size_t)rr * 128 + k) * DOUT + o]
                       : Wroot[(size_t)k * DOUT + o];
    wt[i] = f2b(v);
  }
}

// ---------------- fused layer: out = act( x@Wroot + b + sum_r (A_r x)@W_r ) ----------------

template <int DOUT, bool OUT_BF16>
__launch_bounds__(256)
__global__ void fused_layer(const unsigned short* __restrict__ xb,  // [N][128] bf16
                            const unsigned short* __restrict__ wt,  // [9][DOUT][128] bf16 ([o][k])
                            const int* __restrict__ offs,           // [8N+1]
                            const int* __restrict__ src_s,          // [E]
                            const float* __restrict__ bias,         // [DOUT]
                            unsigned short* __restrict__ out_b,
                            float* __restrict__ out_f,
                            int N) {
  __shared__ unsigned short yl[128 * 136];   // aggregated tile, padded stride
  const unsigned* x32 = (const unsigned*)xb;

  int tid = threadIdx.x, wid = tid >> 6, lane = tid & 63;
  int colb = lane & 15, kgrp = lane >> 4;
  int tilebase = blockIdx.x * 128;

  f32x4 acc[2][DOUT / 16];
#pragma unroll
  for (int t = 0; t < 2; ++t)
#pragma unroll
    for (int nf = 0; nf < DOUT / 16; ++nf) {
      f32x4 z = {0.f, 0.f, 0.f, 0.f};
      acc[t][nf] = z;
    }

  // ---- root transform: A from global x, B from global wt[8] ----
  {
    const unsigned short* wr = wt + (size_t)8 * DOUT * 128;
    int ra = tilebase + wid * 32 + colb;
    int rb = ra + 16;
    const unsigned short* pa = xb + (size_t)(ra < N ? ra : 0) * 128;
    const unsigned short* pb = xb + (size_t)(rb < N ? rb : 0) * 128;
#pragma unroll
    for (int kk = 0; kk < 4; ++kk) {
      int kbase = kk * 32 + kgrp * 8;
      bf16x8 a0 = *(const bf16x8*)(pa + kbase);
      bf16x8 a1 = *(const bf16x8*)(pb + kbase);
#pragma unroll
      for (int nf = 0; nf < DOUT / 16; ++nf) {
        bf16x8 b = *(const bf16x8*)(wr + (size_t)(nf * 16 + colb) * 128 + kbase);
        acc[0][nf] = __builtin_amdgcn_mfma_f32_16x16x32_bf16(a0, b, acc[0][nf], 0, 0, 0);
        acc[1][nf] = __builtin_amdgcn_mfma_f32_16x16x32_bf16(a1, b, acc[1][nf], 0, 0, 0);
      }
    }
  }

  // ---- 8 relations: aggregate into LDS, then MFMA ----
  for (int r = 0; r < 8; ++r) {
    __syncthreads();   // previous iteration's MFMA reads of yl are done
    for (int row = wid; row < 128; row += 4) {
      int d = tilebase + row;
      float s0 = 0.f, s1 = 0.f;
      if (d < N) {
        int key = r * N + d;
        int lo = offs[key], hi = offs[key + 1];
        int i = lo;
        for (; i + 4 <= hi; i += 4) {
          int sA = src_s[i], sB = src_s[i + 1], sC = src_s[i + 2], sD = src_s[i + 3];
          unsigned vA = x32[(size_t)sA * 64 + lane];
          unsigned vB = x32[(size_t)sB * 64 + lane];
          unsigned vC = x32[(size_t)sC * 64 + lane];
          unsigned vD = x32[(size_t)sD * 64 + lane];
          s0 += b2f((unsigned short)(vA & 0xFFFFu)) + b2f((unsigned short)(vB & 0xFFFFu))
              + b2f((unsigned short)(vC & 0xFFFFu)) + b2f((unsigned short)(vD & 0xFFFFu));
          s1 += b2f((unsigned short)(vA >> 16)) + b2f((unsigned short)(vB >> 16))
              + b2f((unsigned short)(vC >> 16)) + b2f((unsigned short)(vD >> 16));
        }
        for (; i < hi; ++i) {
          unsigned v = x32[(size_t)src_s[i] * 64 + lane];
          s0 += b2f((unsigned short)(v & 0xFFFFu));
          s1 += b2f((unsigned short)(v >> 16));
        }
      }
      unsigned pk = (unsigned)f2b(s0) | ((unsigned)f2b(s1) << 16);
      *(unsigned*)(yl + row * 136 + lane * 2) = pk;
    }
    __syncthreads();

    const unsigned short* wr = wt + (size_t)r * DOUT * 128;
#pragma unroll
    for (int kk = 0; kk < 4; ++kk) {
      int kbase = kk * 32 + kgrp * 8;
      bf16x8 a0 = *(const bf16x8*)(yl + (wid * 32 + colb) * 136 + kbase);
      bf16x8 a1 = *(const bf16x8*)(yl + (wid * 32 + colb + 16) * 136 + kbase);
#pragma unroll
      for (int nf = 0; nf < DOUT / 16; ++nf) {
        bf16x8 b = *(const bf16x8*)(wr + (size_t)(nf * 16 + colb) * 128 + kbase);
        acc[0][nf] = __builtin_amdgcn_mfma_f32_16x16x32_bf16(a0, b, acc[0][nf], 0, 0, 0);
        acc[1][nf] = __builtin_amdgcn_mfma_f32_16x16x32_bf16(a1, b, acc[1][nf], 0, 0, 0);
      }
    }
  }

  // ---- epilogue: bias (+relu+bf16) ----
  float bv[DOUT / 16];
#pragma unroll
  for (int nf = 0; nf < DOUT / 16; ++nf) bv[nf] = bias[nf * 16 + colb];

  int rsub = kgrp * 4;
#pragma unroll
  for (int t = 0; t < 2; ++t) {
#pragma unroll
    for (int i = 0; i < 4; ++i) {
      int row = tilebase + wid * 32 + t * 16 + rsub + i;
      if (row >= N) continue;
#pragma unroll
      for (int nf = 0; nf < DOUT / 16; ++nf) {
        int col = nf * 16 + colb;
        float v = acc[t][nf][i] + bv[nf];
        if (OUT_BF16) out_b[(size_t)row * DOUT + col] = f2b(fmaxf(v, 0.f));
        else out_f[(size_t)row * DOUT + col] = v;
      }
    }
  }
}

// ---------------- input cast, log-softmax ----------------

__global__ void cast_kernel(const float* __restrict__ in, unsigned short* __restrict__ out,
                            int n4) {
  int stride = gridDim.x * blockDim.x;
  for (int i = blockIdx.x * blockDim.x + threadIdx.x; i < n4; i += stride) {
    float4 v = ((const float4*)in)[i];
    ushort4 o;
    o.x = f2b(v.x); o.y = f2b(v.y); o.z = f2b(v.z); o.w = f2b(v.w);
    ((ushort4*)out)[i] = o;
  }
}

__global__ void lsm_kernel(const float* __restrict__ acc, float* __restrict__ out, int nrows) {
  int lane = threadIdx.x & 63;
  int row = (blockIdx.x * blockDim.x + threadIdx.x) >> 6;
  if (row >= nrows) return;
  float v = acc[(size_t)row * 64 + lane];
  float m = v;
#pragma unroll
  for (int s = 32; s; s >>= 1) m = fmaxf(m, __shfl_xor(m, s));
  float e = __expf(v - m);
  float sum = e;
#pragma unroll
  for (int s = 32; s; s >>= 1) sum += __shfl_xor(sum, s);
  out[(size_t)row * 64 + lane] = v - m - __logf(sum);
}

// ---------------- launch ----------------

extern "C" void kernel_launch(void* const* d_in, const int* in_sizes, int n_in,
                              void* d_out, int out_size, void* d_ws, size_t ws_size,
                              hipStream_t stream) {
  const float* x = (const float*)d_in[0];
  const int* eidx = (const int*)d_in[1];     // int32
  const int* et = (const int*)d_in[2];       // int32
  const float* Wrel1 = (const float*)d_in[3];
  const float* Wroot1 = (const float*)d_in[4];
  const float* b1 = (const float*)d_in[5];
  const float* Wrel2 = (const float*)d_in[6];
  const float* Wroot2 = (const float*)d_in[7];
  const float* b2 = (const float*)d_in[8];
  const float* Wrel3 = (const float*)d_in[9];
  const float* Wroot3 = (const float*)d_in[10];
  const float* b3 = (const float*)d_in[11];

  const int N = in_sizes[0] / 128;    // 100000
  const int E = in_sizes[2];          // 1600000
  const int KT = 8 * N;
  const int* esrc = eidx;
  const int* edst = eidx + E;

  char* p = (char*)d_ws;
  auto carve = [&](size_t bytes) {
    void* q = (void*)p;
    p += (bytes + 255) & ~(size_t)255;
    return q;
  };
  unsigned short* bufX0 = (unsigned short*)carve((size_t)N * 128 * 2);
  unsigned short* bufX1 = (unsigned short*)carve((size_t)N * 128 * 2);
  float* Acc = (float*)carve((size_t)N * 64 * 4);
  unsigned short* wt1 = (unsigned short*)carve((size_t)9 * 128 * 128 * 2);
  unsigned short* wt2 = (unsigned short*)carve((size_t)9 * 128 * 128 * 2);
  unsigned short* wt3 = (unsigned short*)carve((size_t)9 * 64 * 128 * 2);
  int* src_s = (int*)carve((size_t)E * 4);
  int* cnt = (int*)carve((size_t)KT * 4);
  int* offs = (int*)carve((size_t)(KT + 1) * 4);
  int* cursor = (int*)carve((size_t)KT * 4);
  const int nbs = (KT + 255) / 256;
  int* bsum = (int*)carve((size_t)nbs * 4);

  // ---- counting sort of edges by rel*N+dst (once; reused by all 3 layers) ----
  k_zero2<<<2048, 256, 0, stream>>>(cnt, KT);
  k_hist2<<<2048, 256, 0, stream>>>(et, edst, cnt, N, E);
  k_scan1<<<nbs, 256, 0, stream>>>(cnt, offs, bsum, KT);
  k_scan2<<<1, 256, 0, stream>>>(bsum, nbs);
  k_scan3<<<nbs, 256, 0, stream>>>(offs, bsum, cursor, KT, E);
  k_fill2<<<2048, 256, 0, stream>>>(et, esrc, edst, cursor, src_s, N, E);

  // ---- weight prep (all layers upfront) + input cast ----
  wprep_kernel<<<288, 256, 0, stream>>>(Wrel1, Wroot1, wt1, 128);
  wprep_kernel<<<288, 256, 0, stream>>>(Wrel2, Wroot2, wt2, 128);
  wprep_kernel<<<144, 256, 0, stream>>>(Wrel3, Wroot3, wt3, 64);
  cast_kernel<<<2048, 256, 0, stream>>>(x, bufX0, N * 128 / 4);

  const int nblk = (N + 127) / 128;

  fused_layer<128, true><<<nblk, 256, 0, stream>>>(bufX0, wt1, offs, src_s, b1, bufX1, (float*)nullptr, N);
  fused_layer<128, true><<<nblk, 256, 0, stream>>>(bufX1, wt2, offs, src_s, b2, bufX0, (float*)nullptr, N);
  fused_layer<64, false><<<nblk, 256, 0, stream>>>(bufX0, wt3, offs, src_s, b3, (unsigned short*)nullptr, Acc, N);

  lsm_kernel<<<(N * 64 + 255) / 256, 256, 0, stream>>>(Acc, (float*)d_out, N);
}